// Round 1
// baseline (87.609 us; speedup 1.0000x reference)
//
#include <hip/hip_runtime.h>
#include <math.h>

// Problem constants (from reference): B=8, C=32, F=32, K=3, H=W=32
#define NB 8
#define NC 32
#define NF 32
#define NH 32
#define NW 32
#define NQ 9
#define CSPLIT 4            // channel-loop split factor (8 channels per block)
#define CPB (NC / CSPLIT)   // channels per block
#define TROWS 18            // staged padded rows per half-image (16 + 2 halo)
#define TS 34               // padded tile row stride (W+2)
#define TILE_N (TROWS * TS) // 612

typedef float f2 __attribute__((ext_vector_type(2)));
__device__ __forceinline__ f2 sp(float v) { return (f2){v, v}; }

// Block = 256 threads, each owns 2 vertically-adjacent output pixels
// (16 rows x 32 cols = half image). Grid = B*F*2 halves * CSPLIT = 2048
// -> 8 blocks/CU -> 32 waves/CU.
//
// v2 structure: stage ALL 8 channels into LDS up front (19.6 KB/block;
// 8 blocks/CU = 156.7 KB < 160 KB) with ONE __syncthreads per block,
// then a barrier-free compute phase over 72 (q,c) rational evals.
// Replaces the previous per-channel barrier cadence (8 barriers/block,
// each with a vmcnt/lgkmcnt drain every ~400 compute cycles).
// Denominator reciprocals are paired: one v_rcp_f32 (quarter-rate) +
// two v_mul instead of two v_rcp_f32 per (q,c).
__global__ __launch_bounds__(256, 8) void ka_conv_rational_kernel(
    const float* __restrict__ x,     // [B, C, H, W]
    const float* __restrict__ nums,  // [F*Q*C, 6]
    const float* __restrict__ dens,  // [F*Q*C, 4]
    float* __restrict__ out)         // [B, F, H, W]
{
    __shared__ float tile[CPB][TILE_N]; // 8 * 612 * 4 = 19584 B

    const int t    = threadIdx.x;
    const int bid  = blockIdx.x;          // 0..2047
    const int cs   = bid & (CSPLIT - 1);  // channel chunk
    const int half = (bid >> 2) & 1;      // which 16-row half of the image
    const int bf   = bid >> 3;            // = b*NF + f, 0..255
    const int f    = bf & (NF - 1);
    const int bb   = bf >> 5;             // / NF
    const int xx   = t & 31;              // output column
    const int ty   = t >> 5;              // 0..7 -> owns rows 2*ty, 2*ty+1
    const int c0   = cs * CPB;

    // c-invariant staging geometry: element idx of the 18x34 padded tile.
    int  soff[3];
    bool svalid[3];
#pragma unroll
    for (int i = 0; i < 3; ++i) {
        int idx = t + i * 256;
        int ry  = idx / TS;
        int rx  = idx - ry * TS;
        int gy  = half * 16 + ry - 1;
        int gx  = rx - 1;
        bool ok = (idx < TILE_N) && (gy >= 0) && (gy < NH) && (gx >= 0) && (gx < NW);
        svalid[i] = ok;
        soff[i]   = ok ? (gy * NW + gx) : 0; // clamped: always in-bounds
    }

    const float* __restrict__ xb = x + ((size_t)bb * NC + c0) * NH * NW;

    // ---- stage all CPB channels; single barrier for the whole block ----
#pragma unroll
    for (int g = 0; g < CPB; ++g) {
        const float* __restrict__ xc = xb + g * (NH * NW);
        float v0 = xc[soff[0]];
        float v1 = xc[soff[1]];
        float v2 = xc[soff[2]];
        tile[g][t]       = svalid[0] ? v0 : 0.f;
        tile[g][t + 256] = svalid[1] ? v1 : 0.f;
        if (t + 512 < TILE_N)
            tile[g][t + 512] = svalid[2] ? v2 : 0.f;
    }
    __syncthreads(); // the only barrier in the kernel

    const float* __restrict__ abase = nums + (size_t)f * NQ * NC * 6;
    const float* __restrict__ bbase = dens + (size_t)f * NQ * NC * 4;

    f2 acc = {0.f, 0.f};

#pragma unroll 2
    for (int ci = 0; ci < CPB; ++ci) {
        const int c = c0 + ci;
        const float* __restrict__ tl = tile[ci];

        // 4x3 neighborhood covering both pixels' 3x3 windows
        float n[4][3];
#pragma unroll
        for (int dy = 0; dy < 4; ++dy)
#pragma unroll
            for (int dx = 0; dx < 3; ++dx)
                n[dy][dx] = tl[(ty * 2 + dy) * TS + (xx + dx)];

#pragma unroll
        for (int q = 0; q < NQ; ++q) {
            // block-uniform coefficient loads -> scalar (s_load) path
            const float* ap = abase + (size_t)(q * NC + c) * 6;
            const float* bp = bbase + (size_t)(q * NC + c) * 4;
            const float a0 = ap[0], a1 = ap[1], a2 = ap[2],
                        a3 = ap[3], a4 = ap[4], a5 = ap[5];
            const float d0 = bp[0], d1 = bp[1], d2 = bp[2], d3 = bp[3];
            const int qi = q / 3, qj = q - qi * 3;

            // both pixels' terms evaluated as <2 x float> (v_pk_* ops)
            f2 w = {n[qi][qj], n[qi + 1][qj]};
            f2 nu = __builtin_elementwise_fma(sp(a5), w, sp(a4));
            nu = __builtin_elementwise_fma(nu, w, sp(a3));
            nu = __builtin_elementwise_fma(nu, w, sp(a2));
            nu = __builtin_elementwise_fma(nu, w, sp(a1));
            nu = __builtin_elementwise_fma(nu, w, sp(a0));
            f2 dp = __builtin_elementwise_fma(sp(d3), w, sp(d2));
            dp = __builtin_elementwise_fma(dp, w, sp(d1));
            dp = __builtin_elementwise_fma(dp, w, sp(d0));
            dp = dp * w;
            f2 de = 1.0f + __builtin_elementwise_abs(dp);
            // paired reciprocal: 1 quarter-rate v_rcp_f32 + 2 muls
            // (de >= 1 so the product cannot overflow/underflow)
            float pr = de.x * de.y;
            float rr = __builtin_amdgcn_rcpf(pr);
            f2 r;
            r.x = de.y * rr;
            r.y = de.x * rr;
            acc = __builtin_elementwise_fma(nu, r, acc);
        }
    }

    const int y0 = half * 16 + ty * 2;
    float* op = out + ((size_t)bf * NH + y0) * NW + xx;
    unsafeAtomicAdd(op, acc.x);
    unsafeAtomicAdd(op + NW, acc.y);
}

extern "C" void kernel_launch(void* const* d_in, const int* in_sizes, int n_in,
                              void* d_out, int out_size, void* d_ws, size_t ws_size,
                              hipStream_t stream) {
    const float* x    = (const float*)d_in[0];
    const float* nums = (const float*)d_in[1];
    const float* dens = (const float*)d_in[2];
    float* out = (float*)d_out;

    // atomic accumulation target must start at zero (harness poisons d_out)
    hipMemsetAsync(d_out, 0, (size_t)out_size * sizeof(float), stream);

    dim3 grid(NB * NF * 2 * CSPLIT); // 2048 blocks: (b, f, half, csplit)
    dim3 block(256);
    ka_conv_rational_kernel<<<grid, block, 0, stream>>>(x, nums, dens, out);
}